// Round 1
// baseline (2400.630 us; speedup 1.0000x reference)
//
#include <hip/hip_runtime.h>
#include <hip/hip_bf16.h>
#include <math.h>

using hbf = __hip_bfloat16;
typedef __bf16 bf16x8 __attribute__((ext_vector_type(8)));
typedef float f32x4 __attribute__((ext_vector_type(4)));

__device__ inline float wred(float v){
#pragma unroll
  for (int o = 32; o > 0; o >>= 1) v += __shfl_xor(v, o);
  return v;
}
__device__ inline float r16(float v){
  v += __shfl_xor(v, 1); v += __shfl_xor(v, 2);
  v += __shfl_xor(v, 4); v += __shfl_xor(v, 8);
  return v;
}
__device__ inline float fast_rcp(float x){
  float r; asm("v_rcp_f32 %0, %1" : "=v"(r) : "v"(x)); return r;
}
__device__ inline float d4(const float4& a, const float4& b){
  return a.x*b.x + a.y*b.y + a.z*b.z + a.w*b.w;
}

// ---------------- init: zero the two accumulators (ws is poisoned 0xAA once) ----
__global__ void k_init(float* scal){
  if (threadIdx.x < 2) scal[threadIdx.x] = 0.f;
}

// ---------------- fused distances / softmax / agg / vq loss --------------------
// one block per batch; 8 waves; wave w handles tokens n = it*8 + w
__global__ __launch_bounds__(512) void k_dist(const float* __restrict__ x,
    const float* __restrict__ vqcb, const float* __restrict__ agcb,
    hbf* __restrict__ aggbf, float* __restrict__ scal){
  __shared__ float cA[5376];
  __shared__ float cV[5376];
  __shared__ float sqA[7], sqV[7];
  const int tid = threadIdx.x, lane = tid & 63, wave = tid >> 6;
  const int b = blockIdx.x;
  for (int i = tid; i < 5376; i += 512){ cA[i] = agcb[i]; cV[i] = vqcb[i]; }
  __syncthreads();
  {
    int grp = tid >> 4, l16 = tid & 15;
    if (grp < 14){
      const float* s = (grp < 7) ? &cA[grp*768] : &cV[(grp-7)*768];
      float acc = 0.f;
      for (int j = l16; j < 768; j += 16) acc += s[j]*s[j];
      acc = r16(acc);
      if (l16 == 0){ if (grp < 7) sqA[grp] = acc; else sqV[grp-7] = acc; }
    }
  }
  __syncthreads();
  float sqAr[7], sqVr[7];
#pragma unroll
  for (int k = 0; k < 7; ++k){ sqAr[k] = sqA[k]; sqVr[k] = sqV[k]; }

  float4 aR[7][3];
#pragma unroll
  for (int k = 0; k < 7; ++k)
#pragma unroll
    for (int c = 0; c < 3; ++c) aR[k][c] = make_float4(0.f,0.f,0.f,0.f);
  float loss = 0.f;

  const float* xb = x + (size_t)b*196*768;
  float4 cx0, cx1, cx2, nx0, nx1, nx2;
  { const float* p = xb + (size_t)wave*768 + (lane<<2);
    cx0 = *(const float4*)(p); cx1 = *(const float4*)(p+256); cx2 = *(const float4*)(p+512); }
  for (int it = 0; it < 25; ++it){
    const int n = it*8 + wave;
    const int nn = n + 8;
    if (nn < 196){
      const float* p = xb + (size_t)nn*768 + (lane<<2);
      nx0 = *(const float4*)(p); nx1 = *(const float4*)(p+256); nx2 = *(const float4*)(p+512);
    }
    if (n < 196){
      float xsq = d4(cx0,cx0)+d4(cx1,cx1)+d4(cx2,cx2);
      float dA[7], dV[7];
#pragma unroll
      for (int k = 0; k < 7; ++k){
        const float4* pa = (const float4*)&cA[k*768];
        const float4* pv = (const float4*)&cV[k*768];
        float4 a0 = pa[lane], a1 = pa[64+lane], a2 = pa[128+lane];
        float4 q0 = pv[lane], q1 = pv[64+lane], q2 = pv[128+lane];
        dA[k] = d4(cx0,a0)+d4(cx1,a1)+d4(cx2,a2);
        dV[k] = d4(cx0,q0)+d4(cx1,q1)+d4(cx2,q2);
      }
      xsq = wred(xsq);
#pragma unroll
      for (int k = 0; k < 7; ++k){ dA[k] = wred(dA[k]); dV[k] = wred(dV[k]); }
      float lg[7], mx = -1e30f;
#pragma unroll
      for (int k = 0; k < 7; ++k){ lg[k] = 2.f*dA[k] - sqAr[k]; mx = fmaxf(mx, lg[k]); }
      float pr[7], ssum = 0.f;
#pragma unroll
      for (int k = 0; k < 7; ++k){ pr[k] = expf(lg[k]-mx); ssum += pr[k]; }
      const float inv = 1.f/ssum;
      float mn = 1e30f;
#pragma unroll
      for (int k = 0; k < 7; ++k) mn = fminf(mn, sqVr[k] - 2.f*dV[k]);
      loss += xsq + mn;
#pragma unroll
      for (int k = 0; k < 7; ++k){
        const float w = pr[k]*inv;
        aR[k][0].x += w*cx0.x; aR[k][0].y += w*cx0.y; aR[k][0].z += w*cx0.z; aR[k][0].w += w*cx0.w;
        aR[k][1].x += w*cx1.x; aR[k][1].y += w*cx1.y; aR[k][1].z += w*cx1.z; aR[k][1].w += w*cx1.w;
        aR[k][2].x += w*cx2.x; aR[k][2].y += w*cx2.y; aR[k][2].z += w*cx2.z; aR[k][2].w += w*cx2.w;
      }
    }
    cx0 = nx0; cx1 = nx1; cx2 = nx2;
  }
  __syncthreads();
  for (int i = tid; i < 5376; i += 512) cA[i] = 0.f;
  __syncthreads();
  for (int w = 0; w < 8; ++w){
    if (wave == w){
#pragma unroll
      for (int k = 0; k < 7; ++k)
#pragma unroll
        for (int c = 0; c < 3; ++c){
          float* p = &cA[k*768 + c*256 + (lane<<2)];
          p[0] += aR[k][c].x; p[1] += aR[k][c].y; p[2] += aR[k][c].z; p[3] += aR[k][c].w;
        }
    }
    __syncthreads();
  }
  for (int i = tid; i < 5376; i += 512) aggbf[(size_t)b*5376 + i] = __float2bfloat16(cA[i]);
  if (lane == 0) atomicAdd(&scal[0], loss);
}

// ---------------- Gram: G = X Xtr per batch, bf16 MFMA, X staged in LDS --------
__global__ __launch_bounds__(512) void k_gram(const float* __restrict__ x, float* __restrict__ G){
  __shared__ hbf Xs[208*104];
  const int tid = threadIdx.x, lane = tid & 63, wave = tid >> 6;
  const int b = blockIdx.x;
  const int l15 = lane & 15;
  const int fr0 = wave, fr1 = wave + 8;
  const bool f1 = (fr1 < 13);
  f32x4 acc0[13] = {};
  f32x4 acc1[13] = {};
  const float* xb = x + (size_t)b*196*768;
  for (int kc = 0; kc < 8; ++kc){
    __syncthreads();
    for (int u = tid; u < 4992; u += 512){
      const int r = u / 24, c4 = u - r*24;
      ushort4 val;
      if (r < 196){
        float4 f = *(const float4*)(xb + (size_t)r*768 + kc*96 + c4*4);
        hbf t0 = __float2bfloat16(f.x), t1 = __float2bfloat16(f.y);
        hbf t2 = __float2bfloat16(f.z), t3 = __float2bfloat16(f.w);
        val.x = *(const unsigned short*)&t0; val.y = *(const unsigned short*)&t1;
        val.z = *(const unsigned short*)&t2; val.w = *(const unsigned short*)&t3;
      } else { val.x = 0; val.y = 0; val.z = 0; val.w = 0; }
      *(ushort4*)&Xs[r*104 + c4*4] = val;
    }
    __syncthreads();
#pragma unroll
    for (int kk = 0; kk < 3; ++kk){
      const int ko = kk*32 + (lane>>4)*8;
      bf16x8 a0 = *(const bf16x8*)&Xs[(fr0*16 + l15)*104 + ko];
      bf16x8 a1 = f1 ? *(const bf16x8*)&Xs[(fr1*16 + l15)*104 + ko] : a0;
#pragma unroll
      for (int fc = 0; fc < 13; ++fc){
        bf16x8 bb = *(const bf16x8*)&Xs[(fc*16 + l15)*104 + ko];
        acc0[fc] = __builtin_amdgcn_mfma_f32_16x16x32_bf16(a0, bb, acc0[fc], 0, 0, 0);
        if (f1) acc1[fc] = __builtin_amdgcn_mfma_f32_16x16x32_bf16(a1, bb, acc1[fc], 0, 0, 0);
      }
    }
  }
  const size_t gb = (size_t)b*38416;
  const int cr = (lane>>4)*4;
#pragma unroll
  for (int fc = 0; fc < 13; ++fc){
    const int gc = fc*16 + l15;
    if (gc < 196){
#pragma unroll
      for (int r = 0; r < 4; ++r){
        const int gr = fr0*16 + cr + r;
        if (gr < 196) G[gb + (size_t)gr*196 + gc] = acc0[fc][r];
      }
      if (f1){
#pragma unroll
        for (int r = 0; r < 4; ++r){
          const int gr = fr1*16 + cr + r;
          if (gr < 196) G[gb + (size_t)gr*196 + gc] = acc1[fc][r];
        }
      }
    }
  }
}

// ---------------- eigen: Householder tridiag in LDS + Sturm bisection ----------
__global__ __launch_bounds__(256) void k_eigen(const float* __restrict__ G, float* __restrict__ scal){
  extern __shared__ float S[];
  float* A  = S;              // 196*197
  float* vv = S + 38612;
  float* ww = vv + 196;
  float* dd = ww + 196;
  float* ee = dd + 196;
  float* e2 = ee + 196;
  float* red = e2 + 196;      // 16
  const int n = 196;
  const int tid = threadIdx.x, lane = tid & 63, wave = tid >> 6;
  const int b = blockIdx.x;
  const size_t gb = (size_t)b*38416;
  for (int u = tid; u < 38416; u += 256){
    const int r = u / 196, c = u - r*196;
    A[r*197 + c] = G[gb + u];
  }
  __syncthreads();
  for (int k = 0; k <= n-3; ++k){
    const int base = k + 1, m = n - 1 - k;
    float xi = 0.f;
    if (tid < m) xi = A[(base+tid)*197 + k];
    float p = (tid >= 1 && tid < m) ? xi*xi : 0.f;
    p = wred(p);
    if (lane == 0) red[wave] = p;
    __syncthreads();
    if (tid == 0){
      const float sigma = red[0]+red[1]+red[2]+red[3];
      const float x0 = A[base*197 + k];
      float tau = 0.f, v0 = 0.f, alpha = x0;
      if (sigma > 1e-20f){
        const float mu = sqrtf(x0*x0 + sigma);
        alpha = (x0 > 0.f) ? -mu : mu;
        v0 = x0 - alpha;
        tau = 2.f/(sigma + v0*v0);
      }
      ee[k] = alpha; red[8] = tau; red[9] = v0;
    }
    __syncthreads();
    const float tau = red[8];
    if (tid < m) vv[tid] = (tid == 0) ? red[9] : xi;
    __syncthreads();
    if (tau != 0.f){
      const int g = lane >> 4, l16v = lane & 15;
      for (int i = wave*4 + g; i < m; i += 16){
        const float* Ar = &A[(size_t)(base+i)*197 + base];
        float s = 0.f;
        for (int j = l16v; j < m; j += 16) s += Ar[j]*vv[j];
        s = r16(s);
        if (l16v == 0) ww[i] = tau*s;
      }
      __syncthreads();
      float q = (tid < m) ? vv[tid]*ww[tid] : 0.f;
      q = wred(q);
      if (lane == 0) red[wave] = q;
      __syncthreads();
      if (tid == 0) red[10] = 0.5f*tau*(red[0]+red[1]+red[2]+red[3]);
      __syncthreads();
      const float c2 = red[10];
      if (tid < m) ww[tid] -= c2*vv[tid];
      __syncthreads();
      for (int i = wave; i < m; i += 4){
        const float vi = vv[i], wi = ww[i];
        float* Ar = &A[(size_t)(base+i)*197 + base];
        for (int j = lane; j < m; j += 64)
          Ar[j] -= vi*ww[j] + wi*vv[j];
      }
      __syncthreads();
    }
  }
  __syncthreads();
  if (tid < n) dd[tid] = A[tid*197 + tid];
  if (tid == 0) ee[n-2] = A[(size_t)(n-1)*197 + (n-2)];
  __syncthreads();
  if (tid < n-1) e2[tid] = ee[tid]*ee[tid];
  __syncthreads();
  float lo = 1e30f, hi = -1e30f;
  if (tid < n){
    const float rr = ((tid > 0) ? fabsf(ee[tid-1]) : 0.f) + ((tid < n-1) ? fabsf(ee[tid]) : 0.f);
    lo = dd[tid] - rr; hi = dd[tid] + rr;
  }
  {
    float l2 = lo, h2 = hi;
#pragma unroll
    for (int o = 32; o > 0; o >>= 1){
      l2 = fminf(l2, __shfl_xor(l2, o));
      h2 = fmaxf(h2, __shfl_xor(h2, o));
    }
    if (lane == 0){ red[wave] = l2; red[4+wave] = h2; }
  }
  __syncthreads();
  if (tid == 0){
    red[8] = fminf(fminf(red[0], red[1]), fminf(red[2], red[3]));
    red[9] = fmaxf(fmaxf(red[4], red[5]), fmaxf(red[6], red[7]));
  }
  __syncthreads();
  float sv = 0.f;
  if (tid < n){
    float lob = red[8], hib = red[9];
    for (int it2 = 0; it2 < 26; ++it2){
      const float mid = 0.5f*(lob + hib);
      float q = dd[0] - mid;
      int cnt = (q < 0.f) ? 1 : 0;
      for (int i = 1; i < n; ++i){
        const float r = fast_rcp(q);
        q = (dd[i] - mid) - e2[i-1]*r;
        q = (fabsf(q) < 1e-6f) ? -1e-6f : q;
        cnt += (q < 0.f) ? 1 : 0;
      }
      if (cnt <= tid) lob = mid; else hib = mid;
    }
    sv = sqrtf(fmaxf(0.5f*(lob + hib), 0.f));
  }
  __syncthreads();
  if (tid < n) vv[tid] = sv;
  __syncthreads();
  if (tid == 0){
    float tot = 0.f;
    for (int i = 0; i < n; ++i) tot += vv[i];
    const float thr = 0.99f*tot;
    float cs = 0.f; int rank = 0;
    for (int i = n-1; i >= 0; --i){ cs += vv[i]; rank += (cs <= thr) ? 1 : 0; }
    atomicAdd(&scal[1], (float)rank);
  }
}

// ---------------- transpose + f32->bf16 for weights ----------------------------
__global__ __launch_bounds__(256) void k_tr(const float* __restrict__ in, hbf* __restrict__ outp,
                                            int Rr, int Cc){
  __shared__ float t[32][33];
  const int tid = threadIdx.x;
  const int lc = tid & 31, lr = tid >> 5;
  const int c0 = blockIdx.x*32, r0 = blockIdx.y*32;
#pragma unroll
  for (int i = 0; i < 4; ++i)
    t[lr + i*8][lc] = in[(size_t)(r0 + lr + i*8)*Cc + c0 + lc];
  __syncthreads();
#pragma unroll
  for (int i = 0; i < 4; ++i)
    outp[(size_t)(c0 + lr + i*8)*Rr + r0 + lc] = __float2bfloat16(t[lc][lr + i*8]);
}

// ---------------- GEMM: A[M,K] * B^T[N,K], bf16 MFMA 16x16x32, 64x64 tiles ------
template<int EPI>
__global__ __launch_bounds__(256) void k_gemm(const hbf* __restrict__ Aa, const hbf* __restrict__ Bb,
    const float* __restrict__ bias, void* __restrict__ outp, int Mi, int Ni, int Ki){
  __shared__ hbf As[64*72];
  __shared__ hbf Bs[64*72];
  const int tid = threadIdx.x, lane = tid & 63, wave = tid >> 6;
  const int row0 = blockIdx.y*64, col0 = blockIdx.x*64;
  const int m0 = (wave >> 1)*32, n0 = (wave & 1)*32;
  const int l15 = lane & 15, lk = (lane >> 4)*8;
  const int sr = tid >> 3, sc = (tid & 7)*8;
  f32x4 acc00 = {}, acc01 = {}, acc10 = {}, acc11 = {};
  for (int kt = 0; kt < Ki; kt += 64){
    __syncthreads();
    *(uint4*)&As[sr*72 + sc]        = *(const uint4*)&Aa[(size_t)(row0+sr)*Ki + kt + sc];
    *(uint4*)&As[(sr+32)*72 + sc]   = *(const uint4*)&Aa[(size_t)(row0+sr+32)*Ki + kt + sc];
    *(uint4*)&Bs[sr*72 + sc]        = *(const uint4*)&Bb[(size_t)(col0+sr)*Ki + kt + sc];
    *(uint4*)&Bs[(sr+32)*72 + sc]   = *(const uint4*)&Bb[(size_t)(col0+sr+32)*Ki + kt + sc];
    __syncthreads();
#pragma unroll
    for (int kk = 0; kk < 2; ++kk){
      const int ko = kk*32 + lk;
      bf16x8 a0 = *(const bf16x8*)&As[(m0 + l15)*72 + ko];
      bf16x8 a1 = *(const bf16x8*)&As[(m0 + 16 + l15)*72 + ko];
      bf16x8 b0 = *(const bf16x8*)&Bs[(n0 + l15)*72 + ko];
      bf16x8 b1 = *(const bf16x8*)&Bs[(n0 + 16 + l15)*72 + ko];
      acc00 = __builtin_amdgcn_mfma_f32_16x16x32_bf16(a0, b0, acc00, 0, 0, 0);
      acc01 = __builtin_amdgcn_mfma_f32_16x16x32_bf16(a0, b1, acc01, 0, 0, 0);
      acc10 = __builtin_amdgcn_mfma_f32_16x16x32_bf16(a1, b0, acc10, 0, 0, 0);
      acc11 = __builtin_amdgcn_mfma_f32_16x16x32_bf16(a1, b1, acc11, 0, 0, 0);
    }
  }
  const int cr = (lane >> 4)*4;
#pragma unroll
  for (int i = 0; i < 2; ++i){
#pragma unroll
    for (int j = 0; j < 2; ++j){
      f32x4 av = (i == 0) ? ((j == 0) ? acc00 : acc01) : ((j == 0) ? acc10 : acc11);
      const int gcol = col0 + n0 + j*16 + l15;
#pragma unroll
      for (int r = 0; r < 4; ++r){
        const int grow = row0 + m0 + i*16 + cr + r;
        float v = av[r];
        if (EPI == 1){
          v += bias[gcol];
          v = 0.5f*v*(1.f + erff(v*0.70710678118654752f));
          ((hbf*)outp)[(size_t)grow*Ni + gcol] = __float2bfloat16(v);
        } else if (EPI == 2){
          v += bias[gcol];
          ((float*)outp)[(size_t)grow*Ni + gcol] = v;
        } else {
          ((float*)outp)[(size_t)grow*Ni + gcol] = v;
        }
      }
    }
  }
}

// ---------------- LayerNorm over 768, one wave per row --------------------------
__global__ __launch_bounds__(256) void k_ln(const float* __restrict__ h, const float* __restrict__ gam,
    const float* __restrict__ bet, hbf* __restrict__ hn){
  const int tid = threadIdx.x, lane = tid & 63, wave = tid >> 6;
  const int row = blockIdx.x*4 + wave;
  const float* hr = h + (size_t)row*768;
  const int off = lane*4;
  float4 v0 = *(const float4*)(hr + off);
  float4 v1 = *(const float4*)(hr + 256 + off);
  float4 v2 = *(const float4*)(hr + 512 + off);
  float s = v0.x+v0.y+v0.z+v0.w + v1.x+v1.y+v1.z+v1.w + v2.x+v2.y+v2.z+v2.w;
  s = wred(s);
  const float mu = s*(1.f/768.f);
  float q = 0.f;
  q += (v0.x-mu)*(v0.x-mu); q += (v0.y-mu)*(v0.y-mu); q += (v0.z-mu)*(v0.z-mu); q += (v0.w-mu)*(v0.w-mu);
  q += (v1.x-mu)*(v1.x-mu); q += (v1.y-mu)*(v1.y-mu); q += (v1.z-mu)*(v1.z-mu); q += (v1.w-mu)*(v1.w-mu);
  q += (v2.x-mu)*(v2.x-mu); q += (v2.y-mu)*(v2.y-mu); q += (v2.z-mu)*(v2.z-mu); q += (v2.w-mu)*(v2.w-mu);
  q = wred(q);
  const float rs = 1.f/sqrtf(q*(1.f/768.f) + 1e-5f);
  float4 g0 = *(const float4*)(gam + off), g1 = *(const float4*)(gam + 256 + off), g2 = *(const float4*)(gam + 512 + off);
  float4 t0 = *(const float4*)(bet + off), t1 = *(const float4*)(bet + 256 + off), t2 = *(const float4*)(bet + 512 + off);
  hbf* o = hn + (size_t)row*768;
  o[off+0] = __float2bfloat16((v0.x-mu)*rs*g0.x + t0.x);
  o[off+1] = __float2bfloat16((v0.y-mu)*rs*g0.y + t0.y);
  o[off+2] = __float2bfloat16((v0.z-mu)*rs*g0.z + t0.z);
  o[off+3] = __float2bfloat16((v0.w-mu)*rs*g0.w + t0.w);
  o[256+off+0] = __float2bfloat16((v1.x-mu)*rs*g1.x + t1.x);
  o[256+off+1] = __float2bfloat16((v1.y-mu)*rs*g1.y + t1.y);
  o[256+off+2] = __float2bfloat16((v1.z-mu)*rs*g1.z + t1.z);
  o[256+off+3] = __float2bfloat16((v1.w-mu)*rs*g1.w + t1.w);
  o[512+off+0] = __float2bfloat16((v2.x-mu)*rs*g2.x + t2.x);
  o[512+off+1] = __float2bfloat16((v2.y-mu)*rs*g2.y + t2.y);
  o[512+off+2] = __float2bfloat16((v2.z-mu)*rs*g2.z + t2.z);
  o[512+off+3] = __float2bfloat16((v2.w-mu)*rs*g2.w + t2.w);
}

// ---------------- head: normalize tok, grouped cosine logits, cls ---------------
__global__ __launch_bounds__(256) void k_head(const float* __restrict__ tok, const float* __restrict__ ce,
    const float* __restrict__ clsW, const float* __restrict__ clsb, const float* __restrict__ lgs,
    float* __restrict__ out){
  __shared__ float tkn[7*512];
  __shared__ float il[40];
  const int tid = threadIdx.x, lane = tid & 63, wave = tid >> 6;
  const int b = blockIdx.x;
  const float ls = lgs[0];
  for (int g = wave; g < 7; g += 4){
    const float* tr = tok + (size_t)(b*7 + g)*512;
    float4 u0 = *(const float4*)(tr + (lane<<3));
    float4 u1 = *(const float4*)(tr + (lane<<3) + 4);
    float s = d4(u0,u0) + d4(u1,u1);
    s = wred(s);
    const float inv = 1.f/sqrtf(s);
    float* dst = &tkn[g*512 + (lane<<3)];
    dst[0] = u0.x*inv; dst[1] = u0.y*inv; dst[2] = u0.z*inv; dst[3] = u0.w*inv;
    dst[4] = u1.x*inv; dst[5] = u1.y*inv; dst[6] = u1.z*inv; dst[7] = u1.w*inv;
  }
  __syncthreads();
  for (int c = wave; c < 34; c += 4){
    const int g = (c < 30) ? (c/5) : 6;
    const float* tp = &tkn[g*512 + (lane<<3)];
    const float* cp = ce + (size_t)c*512 + (lane<<3);
    float s = tp[0]*cp[0] + tp[1]*cp[1] + tp[2]*cp[2] + tp[3]*cp[3]
            + tp[4]*cp[4] + tp[5]*cp[5] + tp[6]*cp[6] + tp[7]*cp[7];
    s = wred(s);
    if (lane == 0){
      const float v = ls*s;
      il[c] = v;
      out[1792 + b*34 + c] = v;
    }
  }
  __syncthreads();
  if (tid < 7){
    float s = clsb[tid];
    for (int c = 0; c < 34; ++c) s += il[c]*clsW[c*7 + tid];
    out[b*7 + tid] = s;
  }
}

// ---------------- finalize scalars ----------------------------------------------
__global__ void k_fin(const float* __restrict__ scal, float* __restrict__ out){
  if (threadIdx.x == 0){
    out[10496] = 2.f*scal[0]/(float)(256*196*768);
    out[10497] = scal[1]*(1.f/256.f);
  }
}

extern "C" void kernel_launch(void* const* d_in, const int* in_sizes, int n_in,
                              void* d_out, int out_size, void* d_ws, size_t ws_size,
                              hipStream_t stream) {
  (void)in_sizes; (void)n_in; (void)out_size; (void)ws_size;
  const float* x    = (const float*)d_in[0];
  const float* vqcb = (const float*)d_in[1];
  const float* agcb = (const float*)d_in[2];
  const float* W1   = (const float*)d_in[3];
  const float* b1   = (const float*)d_in[4];
  const float* W2   = (const float*)d_in[5];
  const float* b2   = (const float*)d_in[6];
  const float* gam  = (const float*)d_in[7];
  const float* bet  = (const float*)d_in[8];
  const float* Wp   = (const float*)d_in[9];
  const float* ce   = (const float*)d_in[10];
  const float* clsW = (const float*)d_in[11];
  const float* clsb = (const float*)d_in[12];
  const float* lgs  = (const float*)d_in[13];
  float* out = (float*)d_out;
  char* w = (char*)d_ws;

  // workspace layout (~50 MB): scalars | G (reused later for MLP temps) | aggbf | W1t | W2t | Wpt
  float* scal  = (float*)w;
  float* G     = (float*)(w + 256);
  hbf*   aggbf = (hbf*)(w + 39338240ULL);
  hbf*   W1t   = (hbf*)(w + 42090752ULL);
  hbf*   W2t   = (hbf*)(w + 46809344ULL);
  hbf*   Wpt   = (hbf*)(w + 51527936ULL);
  // reuse of G region (G is dead after k_eigen; all consumers run after it):
  hbf*   h1    = (hbf*)(w + 256);
  float* hbuf  = (float*)(w + 256 + 16777216ULL);
  hbf*   hn    = (hbf*)(w + 256 + 25165824ULL);
  float* tok   = (float*)(w + 256 + 29360128ULL);

  k_init<<<dim3(1), dim3(64), 0, stream>>>(scal);
  k_dist<<<dim3(256), dim3(512), 0, stream>>>(x, vqcb, agcb, aggbf, scal);
  k_gram<<<dim3(256), dim3(512), 0, stream>>>(x, G);
  const int EIG_SMEM = (196*197 + 5*196 + 16)*4; // 158,432 B
  hipFuncSetAttribute((const void*)k_eigen, hipFuncAttributeMaxDynamicSharedMemorySize, EIG_SMEM);
  k_eigen<<<dim3(256), dim3(256), EIG_SMEM, stream>>>(G, scal);
  k_tr<<<dim3(96,24), dim3(256), 0, stream>>>(W1, W1t, 768, 3072);
  k_tr<<<dim3(24,96), dim3(256), 0, stream>>>(W2, W2t, 3072, 768);
  k_tr<<<dim3(16,24), dim3(256), 0, stream>>>(Wp, Wpt, 768, 512);
  k_gemm<1><<<dim3(48,28), dim3(256), 0, stream>>>(aggbf, W1t, b1, (void*)h1, 1792, 3072, 768);
  k_gemm<2><<<dim3(12,28), dim3(256), 0, stream>>>(h1, W2t, b2, (void*)hbuf, 1792, 768, 3072);
  k_ln<<<dim3(448), dim3(256), 0, stream>>>(hbuf, gam, bet, hn);
  k_gemm<3><<<dim3(8,28), dim3(256), 0, stream>>>(hn, Wpt, nullptr, (void*)tok, 1792, 512, 768);
  k_head<<<dim3(256), dim3(256), 0, stream>>>(tok, ce, clsW, clsb, lgs, out);
  k_fin<<<dim3(1), dim3(64), 0, stream>>>(scal, out);
}

// Round 3
// 1469.736 us; speedup vs baseline: 1.6334x; 1.6334x over previous
//
#include <hip/hip_runtime.h>
#include <hip/hip_bf16.h>
#include <math.h>

using hbf = __hip_bfloat16;
typedef __bf16 bf16x8 __attribute__((ext_vector_type(8)));
typedef float f32x4 __attribute__((ext_vector_type(4)));

__device__ inline float wred(float v){
#pragma unroll
  for (int o = 32; o > 0; o >>= 1) v += __shfl_xor(v, o);
  return v;
}
__device__ inline float r16(float v){
  v += __shfl_xor(v, 1); v += __shfl_xor(v, 2);
  v += __shfl_xor(v, 4); v += __shfl_xor(v, 8);
  return v;
}
__device__ inline float fast_rcp(float x){
  float r; asm("v_rcp_f32 %0, %1" : "=v"(r) : "v"(x)); return r;
}
__device__ inline float d4(const float4& a, const float4& b){
  return a.x*b.x + a.y*b.y + a.z*b.z + a.w*b.w;
}

// ---------------- init: zero the two accumulators (ws is poisoned 0xAA once) ----
__global__ void k_init(float* scal){
  if (threadIdx.x < 2) scal[threadIdx.x] = 0.f;
}

// ---------------- fused distances / softmax / agg / vq loss --------------------
// one block per batch; 8 waves; wave w handles tokens n = it*8 + w
__global__ __launch_bounds__(512) void k_dist(const float* __restrict__ x,
    const float* __restrict__ vqcb, const float* __restrict__ agcb,
    hbf* __restrict__ aggbf, float* __restrict__ scal){
  __shared__ float cA[5376];
  __shared__ float cV[5376];
  __shared__ float sqA[7], sqV[7];
  const int tid = threadIdx.x, lane = tid & 63, wave = tid >> 6;
  const int b = blockIdx.x;
  for (int i = tid; i < 5376; i += 512){ cA[i] = agcb[i]; cV[i] = vqcb[i]; }
  __syncthreads();
  {
    int grp = tid >> 4, l16 = tid & 15;
    if (grp < 14){
      const float* s = (grp < 7) ? &cA[grp*768] : &cV[(grp-7)*768];
      float acc = 0.f;
      for (int j = l16; j < 768; j += 16) acc += s[j]*s[j];
      acc = r16(acc);
      if (l16 == 0){ if (grp < 7) sqA[grp] = acc; else sqV[grp-7] = acc; }
    }
  }
  __syncthreads();
  float sqAr[7], sqVr[7];
#pragma unroll
  for (int k = 0; k < 7; ++k){ sqAr[k] = sqA[k]; sqVr[k] = sqV[k]; }

  float4 aR[7][3];
#pragma unroll
  for (int k = 0; k < 7; ++k)
#pragma unroll
    for (int c = 0; c < 3; ++c) aR[k][c] = make_float4(0.f,0.f,0.f,0.f);
  float loss = 0.f;

  const float* xb = x + (size_t)b*196*768;
  float4 cx0, cx1, cx2, nx0, nx1, nx2;
  { const float* p = xb + (size_t)wave*768 + (lane<<2);
    cx0 = *(const float4*)(p); cx1 = *(const float4*)(p+256); cx2 = *(const float4*)(p+512); }
  for (int it = 0; it < 25; ++it){
    const int n = it*8 + wave;
    const int nn = n + 8;
    if (nn < 196){
      const float* p = xb + (size_t)nn*768 + (lane<<2);
      nx0 = *(const float4*)(p); nx1 = *(const float4*)(p+256); nx2 = *(const float4*)(p+512);
    }
    if (n < 196){
      float xsq = d4(cx0,cx0)+d4(cx1,cx1)+d4(cx2,cx2);
      float dA[7], dV[7];
#pragma unroll
      for (int k = 0; k < 7; ++k){
        const float4* pa = (const float4*)&cA[k*768];
        const float4* pv = (const float4*)&cV[k*768];
        float4 a0 = pa[lane], a1 = pa[64+lane], a2 = pa[128+lane];
        float4 q0 = pv[lane], q1 = pv[64+lane], q2 = pv[128+lane];
        dA[k] = d4(cx0,a0)+d4(cx1,a1)+d4(cx2,a2);
        dV[k] = d4(cx0,q0)+d4(cx1,q1)+d4(cx2,q2);
      }
      xsq = wred(xsq);
#pragma unroll
      for (int k = 0; k < 7; ++k){ dA[k] = wred(dA[k]); dV[k] = wred(dV[k]); }
      float lg[7], mx = -1e30f;
#pragma unroll
      for (int k = 0; k < 7; ++k){ lg[k] = 2.f*dA[k] - sqAr[k]; mx = fmaxf(mx, lg[k]); }
      float pr[7], ssum = 0.f;
#pragma unroll
      for (int k = 0; k < 7; ++k){ pr[k] = expf(lg[k]-mx); ssum += pr[k]; }
      const float inv = 1.f/ssum;
      float mn = 1e30f;
#pragma unroll
      for (int k = 0; k < 7; ++k) mn = fminf(mn, sqVr[k] - 2.f*dV[k]);
      loss += xsq + mn;
#pragma unroll
      for (int k = 0; k < 7; ++k){
        const float w = pr[k]*inv;
        aR[k][0].x += w*cx0.x; aR[k][0].y += w*cx0.y; aR[k][0].z += w*cx0.z; aR[k][0].w += w*cx0.w;
        aR[k][1].x += w*cx1.x; aR[k][1].y += w*cx1.y; aR[k][1].z += w*cx1.z; aR[k][1].w += w*cx1.w;
        aR[k][2].x += w*cx2.x; aR[k][2].y += w*cx2.y; aR[k][2].z += w*cx2.z; aR[k][2].w += w*cx2.w;
      }
    }
    cx0 = nx0; cx1 = nx1; cx2 = nx2;
  }
  __syncthreads();
  for (int i = tid; i < 5376; i += 512) cA[i] = 0.f;
  __syncthreads();
  for (int w = 0; w < 8; ++w){
    if (wave == w){
#pragma unroll
      for (int k = 0; k < 7; ++k)
#pragma unroll
        for (int c = 0; c < 3; ++c){
          float* p = &cA[k*768 + c*256 + (lane<<2)];
          p[0] += aR[k][c].x; p[1] += aR[k][c].y; p[2] += aR[k][c].z; p[3] += aR[k][c].w;
        }
    }
    __syncthreads();
  }
  for (int i = tid; i < 5376; i += 512) aggbf[(size_t)b*5376 + i] = __float2bfloat16(cA[i]);
  if (lane == 0) atomicAdd(&scal[0], loss);
}

// ---------------- Gram: G = X Xtr per batch, bf16 MFMA, X staged in LDS --------
__global__ __launch_bounds__(512) void k_gram(const float* __restrict__ x, float* __restrict__ G){
  __shared__ hbf Xs[208*104];
  const int tid = threadIdx.x, lane = tid & 63, wave = tid >> 6;
  const int b = blockIdx.x;
  const int l15 = lane & 15;
  const int fr0 = wave, fr1 = wave + 8;
  const bool f1 = (fr1 < 13);
  f32x4 acc0[13] = {};
  f32x4 acc1[13] = {};
  const float* xb = x + (size_t)b*196*768;
  for (int kc = 0; kc < 8; ++kc){
    __syncthreads();
    for (int u = tid; u < 4992; u += 512){
      const int r = u / 24, c4 = u - r*24;
      ushort4 val;
      if (r < 196){
        float4 f = *(const float4*)(xb + (size_t)r*768 + kc*96 + c4*4);
        hbf t0 = __float2bfloat16(f.x), t1 = __float2bfloat16(f.y);
        hbf t2 = __float2bfloat16(f.z), t3 = __float2bfloat16(f.w);
        val.x = *(const unsigned short*)&t0; val.y = *(const unsigned short*)&t1;
        val.z = *(const unsigned short*)&t2; val.w = *(const unsigned short*)&t3;
      } else { val.x = 0; val.y = 0; val.z = 0; val.w = 0; }
      *(ushort4*)&Xs[r*104 + c4*4] = val;
    }
    __syncthreads();
#pragma unroll
    for (int kk = 0; kk < 3; ++kk){
      const int ko = kk*32 + (lane>>4)*8;
      bf16x8 a0 = *(const bf16x8*)&Xs[(fr0*16 + l15)*104 + ko];
      bf16x8 a1 = f1 ? *(const bf16x8*)&Xs[(fr1*16 + l15)*104 + ko] : a0;
#pragma unroll
      for (int fc = 0; fc < 13; ++fc){
        bf16x8 bb = *(const bf16x8*)&Xs[(fc*16 + l15)*104 + ko];
        acc0[fc] = __builtin_amdgcn_mfma_f32_16x16x32_bf16(a0, bb, acc0[fc], 0, 0, 0);
        if (f1) acc1[fc] = __builtin_amdgcn_mfma_f32_16x16x32_bf16(a1, bb, acc1[fc], 0, 0, 0);
      }
    }
  }
  const size_t gb = (size_t)b*38416;
  const int cr = (lane>>4)*4;
#pragma unroll
  for (int fc = 0; fc < 13; ++fc){
    const int gc = fc*16 + l15;
    if (gc < 196){
#pragma unroll
      for (int r = 0; r < 4; ++r){
        const int gr = fr0*16 + cr + r;
        if (gr < 196) G[gb + (size_t)gr*196 + gc] = acc0[fc][r];
      }
      if (f1){
#pragma unroll
        for (int r = 0; r < 4; ++r){
          const int gr = fr1*16 + cr + r;
          if (gr < 196) G[gb + (size_t)gr*196 + gc] = acc1[fc][r];
        }
      }
    }
  }
}

// ---------------- eigen: Householder tridiag in LDS + Sturm bisection ----------
// 1024 threads (16 waves): wave-per-row matvec/update, per-lane column registers
// (4 tiles, statically unrolled), redundant scalar recomputation (no tid==0 stage).
__global__ __launch_bounds__(1024) void k_eigen(const float* __restrict__ G, float* __restrict__ scal){
  extern __shared__ float S[];
  float* A  = S;              // 196*197
  float* vv = S + 38612;
  float* ww = vv + 200;
  float* dd = ww + 200;
  float* ee = dd + 200;
  float* e2 = ee + 200;
  float* red  = e2 + 200;     // 16
  float* red2 = red + 16;     // 16
  const int n = 196;
  const int tid = threadIdx.x, lane = tid & 63, wave = tid >> 6;
  const int b = blockIdx.x;
  const size_t gb = (size_t)b*38416;
  for (int u = tid; u < 38416; u += 1024){
    const int r = u / 196, c = u - r*196;
    A[r*197 + c] = G[gb + u];
  }
  __syncthreads();
  for (int k = 0; k <= n-3; ++k){
    const int base = k + 1, m = n - 1 - k;   // m <= 195 -> at most 4 column tiles
    // column k (below diag) + its squared norm
    float xi = 0.f;
    if (tid < m) xi = A[(size_t)(base+tid)*197 + k];
    float p = (tid >= 1 && tid < m) ? xi*xi : 0.f;
    p = wred(p);
    if (lane == 0) red[wave] = p;
    __syncthreads();                                   // B1
    float sigma = 0.f;
#pragma unroll
    for (int w2 = 0; w2 < 16; ++w2) sigma += red[w2];
    const float x0 = A[(size_t)base*197 + k];
    float tau = 0.f, v0 = 0.f, alpha = x0;
    if (sigma > 1e-20f){
      const float mu = sqrtf(x0*x0 + sigma);
      alpha = (x0 > 0.f) ? -mu : mu;
      v0 = x0 - alpha;
      tau = 2.f/(sigma + v0*v0);
    }
    if (tid < m) vv[tid] = (tid == 0) ? v0 : xi;
    if (tid == 0) ee[k] = alpha;
    __syncthreads();                                   // B2
    if (tau != 0.f){
      float vj[4];
#pragma unroll
      for (int t = 0; t < 4; ++t){
        const int j = lane + (t<<6);
        vj[t] = (j < m) ? vv[j] : 0.f;
      }
      // matvec: w_raw = tau * A v ; wave per row, partial v^T w per wave
      float cpart = 0.f;
      for (int i = wave; i < m; i += 16){
        const float* Ar = &A[(size_t)(base+i)*197 + base];
        float s = 0.f;
#pragma unroll
        for (int t = 0; t < 4; ++t){
          const int j = lane + (t<<6);
          if (j < m) s += Ar[j]*vj[t];
        }
        s = wred(s);
        if (lane == 0){ const float wr = tau*s; ww[i] = wr; cpart += vv[i]*wr; }
      }
      if (lane == 0) red2[wave] = cpart;
      __syncthreads();                                 // B3
      float vtw = 0.f;
#pragma unroll
      for (int w2 = 0; w2 < 16; ++w2) vtw += red2[w2];
      const float c2 = 0.5f*tau*vtw;
      if (tid < m) ww[tid] -= c2*vv[tid];
      __syncthreads();                                 // B4
      float wj[4];
#pragma unroll
      for (int t = 0; t < 4; ++t){
        const int j = lane + (t<<6);
        wj[t] = (j < m) ? ww[j] : 0.f;
      }
      // rank-2 update: A -= v w^T + w v^T ; wave per row
      for (int i = wave; i < m; i += 16){
        const float vi = vv[i], wi = ww[i];
        float* Ar = &A[(size_t)(base+i)*197 + base];
#pragma unroll
        for (int t = 0; t < 4; ++t){
          const int j = lane + (t<<6);
          if (j < m) Ar[j] -= vi*wj[t] + wi*vj[t];
        }
      }
      __syncthreads();                                 // B5
    }
  }
  if (tid < n) dd[tid] = A[tid*197 + tid];
  if (tid == 0) ee[n-2] = A[(size_t)(n-1)*197 + (n-2)];
  __syncthreads();
  if (tid < n-1) e2[tid] = ee[tid]*ee[tid];
  __syncthreads();
  // Gershgorin bounds
  float lo = 1e30f, hi = -1e30f;
  if (tid < n){
    const float rr = ((tid > 0) ? fabsf(ee[tid-1]) : 0.f) + ((tid < n-1) ? fabsf(ee[tid]) : 0.f);
    lo = dd[tid] - rr; hi = dd[tid] + rr;
  }
  {
    float l2 = lo, h2 = hi;
#pragma unroll
    for (int o = 32; o > 0; o >>= 1){
      l2 = fminf(l2, __shfl_xor(l2, o));
      h2 = fmaxf(h2, __shfl_xor(h2, o));
    }
    if (lane == 0){ red[wave] = l2; red2[wave] = h2; }
  }
  __syncthreads();
  float glo = red[0], ghi = red2[0];
#pragma unroll
  for (int w2 = 1; w2 < 16; ++w2){ glo = fminf(glo, red[w2]); ghi = fmaxf(ghi, red2[w2]); }
  // Sturm bisection: thread tid finds the tid-th smallest eigenvalue
  float sv = 0.f;
  if (tid < n){
    float lob = glo, hib = ghi;
    for (int it2 = 0; it2 < 26; ++it2){
      const float mid = 0.5f*(lob + hib);
      float q = dd[0] - mid;
      int cnt = (q < 0.f) ? 1 : 0;
      for (int i = 1; i < n; ++i){
        const float r = fast_rcp(q);
        q = (dd[i] - mid) - e2[i-1]*r;
        q = (fabsf(q) < 1e-6f) ? -1e-6f : q;
        cnt += (q < 0.f) ? 1 : 0;
      }
      if (cnt <= tid) lob = mid; else hib = mid;
    }
    sv = sqrtf(fmaxf(0.5f*(lob + hib), 0.f));
  }
  __syncthreads();
  if (tid < n) vv[tid] = sv;
  __syncthreads();
  if (tid == 0){
    float tot = 0.f;
    for (int i = 0; i < n; ++i) tot += vv[i];
    const float thr = 0.99f*tot;
    float cs = 0.f; int rank = 0;
    for (int i = n-1; i >= 0; --i){ cs += vv[i]; rank += (cs <= thr) ? 1 : 0; }
    atomicAdd(&scal[1], (float)rank);
  }
}

// ---------------- transpose + f32->bf16 for weights ----------------------------
__global__ __launch_bounds__(256) void k_tr(const float* __restrict__ in, hbf* __restrict__ outp,
                                            int Rr, int Cc){
  __shared__ float t[32][33];
  const int tid = threadIdx.x;
  const int lc = tid & 31, lr = tid >> 5;
  const int c0 = blockIdx.x*32, r0 = blockIdx.y*32;
#pragma unroll
  for (int i = 0; i < 4; ++i)
    t[lr + i*8][lc] = in[(size_t)(r0 + lr + i*8)*Cc + c0 + lc];
  __syncthreads();
#pragma unroll
  for (int i = 0; i < 4; ++i)
    outp[(size_t)(c0 + lr + i*8)*Rr + r0 + lc] = __float2bfloat16(t[lc][lr + i*8]);
}

// ---------------- GEMM: A[M,K] * B^T[N,K], bf16 MFMA 16x16x32, 64x64 tiles ------
template<int EPI>
__global__ __launch_bounds__(256) void k_gemm(const hbf* __restrict__ Aa, const hbf* __restrict__ Bb,
    const float* __restrict__ bias, void* __restrict__ outp, int Mi, int Ni, int Ki){
  __shared__ hbf As[64*72];
  __shared__ hbf Bs[64*72];
  const int tid = threadIdx.x, lane = tid & 63, wave = tid >> 6;
  const int row0 = blockIdx.y*64, col0 = blockIdx.x*64;
  const int m0 = (wave >> 1)*32, n0 = (wave & 1)*32;
  const int l15 = lane & 15, lk = (lane >> 4)*8;
  const int sr = tid >> 3, sc = (tid & 7)*8;
  f32x4 acc00 = {}, acc01 = {}, acc10 = {}, acc11 = {};
  for (int kt = 0; kt < Ki; kt += 64){
    __syncthreads();
    *(uint4*)&As[sr*72 + sc]        = *(const uint4*)&Aa[(size_t)(row0+sr)*Ki + kt + sc];
    *(uint4*)&As[(sr+32)*72 + sc]   = *(const uint4*)&Aa[(size_t)(row0+sr+32)*Ki + kt + sc];
    *(uint4*)&Bs[sr*72 + sc]        = *(const uint4*)&Bb[(size_t)(col0+sr)*Ki + kt + sc];
    *(uint4*)&Bs[(sr+32)*72 + sc]   = *(const uint4*)&Bb[(size_t)(col0+sr+32)*Ki + kt + sc];
    __syncthreads();
#pragma unroll
    for (int kk = 0; kk < 2; ++kk){
      const int ko = kk*32 + lk;
      bf16x8 a0 = *(const bf16x8*)&As[(m0 + l15)*72 + ko];
      bf16x8 a1 = *(const bf16x8*)&As[(m0 + 16 + l15)*72 + ko];
      bf16x8 b0 = *(const bf16x8*)&Bs[(n0 + l15)*72 + ko];
      bf16x8 b1 = *(const bf16x8*)&Bs[(n0 + 16 + l15)*72 + ko];
      acc00 = __builtin_amdgcn_mfma_f32_16x16x32_bf16(a0, b0, acc00, 0, 0, 0);
      acc01 = __builtin_amdgcn_mfma_f32_16x16x32_bf16(a0, b1, acc01, 0, 0, 0);
      acc10 = __builtin_amdgcn_mfma_f32_16x16x32_bf16(a1, b0, acc10, 0, 0, 0);
      acc11 = __builtin_amdgcn_mfma_f32_16x16x32_bf16(a1, b1, acc11, 0, 0, 0);
    }
  }
  const int cr = (lane >> 4)*4;
#pragma unroll
  for (int i = 0; i < 2; ++i){
#pragma unroll
    for (int j = 0; j < 2; ++j){
      f32x4 av = (i == 0) ? ((j == 0) ? acc00 : acc01) : ((j == 0) ? acc10 : acc11);
      const int gcol = col0 + n0 + j*16 + l15;
#pragma unroll
      for (int r = 0; r < 4; ++r){
        const int grow = row0 + m0 + i*16 + cr + r;
        float v = av[r];
        if (EPI == 1){
          v += bias[gcol];
          v = 0.5f*v*(1.f + erff(v*0.70710678118654752f));
          ((hbf*)outp)[(size_t)grow*Ni + gcol] = __float2bfloat16(v);
        } else if (EPI == 2){
          v += bias[gcol];
          ((float*)outp)[(size_t)grow*Ni + gcol] = v;
        } else {
          ((float*)outp)[(size_t)grow*Ni + gcol] = v;
        }
      }
    }
  }
}

// ---------------- LayerNorm over 768, one wave per row --------------------------
__global__ __launch_bounds__(256) void k_ln(const float* __restrict__ h, const float* __restrict__ gam,
    const float* __restrict__ bet, hbf* __restrict__ hn){
  const int tid = threadIdx.x, lane = tid & 63, wave = tid >> 6;
  const int row = blockIdx.x*4 + wave;
  const float* hr = h + (size_t)row*768;
  const int off = lane*4;
  float4 v0 = *(const float4*)(hr + off);
  float4 v1 = *(const float4*)(hr + 256 + off);
  float4 v2 = *(const float4*)(hr + 512 + off);
  float s = v0.x+v0.y+v0.z+v0.w + v1.x+v1.y+v1.z+v1.w + v2.x+v2.y+v2.z+v2.w;
  s = wred(s);
  const float mu = s*(1.f/768.f);
  float q = 0.f;
  q += (v0.x-mu)*(v0.x-mu); q += (v0.y-mu)*(v0.y-mu); q += (v0.z-mu)*(v0.z-mu); q += (v0.w-mu)*(v0.w-mu);
  q += (v1.x-mu)*(v1.x-mu); q += (v1.y-mu)*(v1.y-mu); q += (v1.z-mu)*(v1.z-mu); q += (v1.w-mu)*(v1.w-mu);
  q += (v2.x-mu)*(v2.x-mu); q += (v2.y-mu)*(v2.y-mu); q += (v2.z-mu)*(v2.z-mu); q += (v2.w-mu)*(v2.w-mu);
  q = wred(q);
  const float rs = 1.f/sqrtf(q*(1.f/768.f) + 1e-5f);
  float4 g0 = *(const float4*)(gam + off), g1 = *(const float4*)(gam + 256 + off), g2 = *(const float4*)(gam + 512 + off);
  float4 t0 = *(const float4*)(bet + off), t1 = *(const float4*)(bet + 256 + off), t2 = *(const float4*)(bet + 512 + off);
  hbf* o = hn + (size_t)row*768;
  o[off+0] = __float2bfloat16((v0.x-mu)*rs*g0.x + t0.x);
  o[off+1] = __float2bfloat16((v0.y-mu)*rs*g0.y + t0.y);
  o[off+2] = __float2bfloat16((v0.z-mu)*rs*g0.z + t0.z);
  o[off+3] = __float2bfloat16((v0.w-mu)*rs*g0.w + t0.w);
  o[256+off+0] = __float2bfloat16((v1.x-mu)*rs*g1.x + t1.x);
  o[256+off+1] = __float2bfloat16((v1.y-mu)*rs*g1.y + t1.y);
  o[256+off+2] = __float2bfloat16((v1.z-mu)*rs*g1.z + t1.z);
  o[256+off+3] = __float2bfloat16((v1.w-mu)*rs*g1.w + t1.w);
  o[512+off+0] = __float2bfloat16((v2.x-mu)*rs*g2.x + t2.x);
  o[512+off+1] = __float2bfloat16((v2.y-mu)*rs*g2.y + t2.y);
  o[512+off+2] = __float2bfloat16((v2.z-mu)*rs*g2.z + t2.z);
  o[512+off+3] = __float2bfloat16((v2.w-mu)*rs*g2.w + t2.w);
}

// ---------------- head: normalize tok, grouped cosine logits, cls ---------------
__global__ __launch_bounds__(256) void k_head(const float* __restrict__ tok, const float* __restrict__ ce,
    const float* __restrict__ clsW, const float* __restrict__ clsb, const float* __restrict__ lgs,
    float* __restrict__ out){
  __shared__ float tkn[7*512];
  __shared__ float il[40];
  const int tid = threadIdx.x, lane = tid & 63, wave = tid >> 6;
  const int b = blockIdx.x;
  const float ls = lgs[0];
  for (int g = wave; g < 7; g += 4){
    const float* tr = tok + (size_t)(b*7 + g)*512;
    float4 u0 = *(const float4*)(tr + (lane<<3));
    float4 u1 = *(const float4*)(tr + (lane<<3) + 4);
    float s = d4(u0,u0) + d4(u1,u1);
    s = wred(s);
    const float inv = 1.f/sqrtf(s);
    float* dst = &tkn[g*512 + (lane<<3)];
    dst[0] = u0.x*inv; dst[1] = u0.y*inv; dst[2] = u0.z*inv; dst[3] = u0.w*inv;
    dst[4] = u1.x*inv; dst[5] = u1.y*inv; dst[6] = u1.z*inv; dst[7] = u1.w*inv;
  }
  __syncthreads();
  for (int c = wave; c < 34; c += 4){
    const int g = (c < 30) ? (c/5) : 6;
    const float* tp = &tkn[g*512 + (lane<<3)];
    const float* cp = ce + (size_t)c*512 + (lane<<3);
    float s = tp[0]*cp[0] + tp[1]*cp[1] + tp[2]*cp[2] + tp[3]*cp[3]
            + tp[4]*cp[4] + tp[5]*cp[5] + tp[6]*cp[6] + tp[7]*cp[7];
    s = wred(s);
    if (lane == 0){
      const float v = ls*s;
      il[c] = v;
      out[1792 + b*34 + c] = v;
    }
  }
  __syncthreads();
  if (tid < 7){
    float s = clsb[tid];
    for (int c = 0; c < 34; ++c) s += il[c]*clsW[c*7 + tid];
    out[b*7 + tid] = s;
  }
}

// ---------------- finalize scalars ----------------------------------------------
__global__ void k_fin(const float* __restrict__ scal, float* __restrict__ out){
  if (threadIdx.x == 0){
    out[10496] = 2.f*scal[0]/(float)(256*196*768);
    out[10497] = scal[1]*(1.f/256.f);
  }
}

extern "C" void kernel_launch(void* const* d_in, const int* in_sizes, int n_in,
                              void* d_out, int out_size, void* d_ws, size_t ws_size,
                              hipStream_t stream) {
  (void)in_sizes; (void)n_in; (void)out_size; (void)ws_size;
  const float* x    = (const float*)d_in[0];
  const float* vqcb = (const float*)d_in[1];
  const float* agcb = (const float*)d_in[2];
  const float* W1   = (const float*)d_in[3];
  const float* b1   = (const float*)d_in[4];
  const float* W2   = (const float*)d_in[5];
  const float* b2   = (const float*)d_in[6];
  const float* gam  = (const float*)d_in[7];
  const float* bet  = (const float*)d_in[8];
  const float* Wp   = (const float*)d_in[9];
  const float* ce   = (const float*)d_in[10];
  const float* clsW = (const float*)d_in[11];
  const float* clsb = (const float*)d_in[12];
  const float* lgs  = (const float*)d_in[13];
  float* out = (float*)d_out;
  char* w = (char*)d_ws;

  // workspace layout (~50 MB): scalars | G (reused later for MLP temps) | aggbf | W1t | W2t | Wpt
  float* scal  = (float*)w;
  float* G     = (float*)(w + 256);
  hbf*   aggbf = (hbf*)(w + 39338240ULL);
  hbf*   W1t   = (hbf*)(w + 42090752ULL);
  hbf*   W2t   = (hbf*)(w + 46809344ULL);
  hbf*   Wpt   = (hbf*)(w + 51527936ULL);
  // reuse of G region (G is dead after k_eigen; all consumers run after it):
  hbf*   h1    = (hbf*)(w + 256);
  float* hbuf  = (float*)(w + 256 + 16777216ULL);
  hbf*   hn    = (hbf*)(w + 256 + 25165824ULL);
  float* tok   = (float*)(w + 256 + 29360128ULL);

  k_init<<<dim3(1), dim3(64), 0, stream>>>(scal);
  k_dist<<<dim3(256), dim3(512), 0, stream>>>(x, vqcb, agcb, aggbf, scal);
  k_gram<<<dim3(256), dim3(512), 0, stream>>>(x, G);
  const int EIG_SMEM = (196*197 + 5*200 + 32)*4; // 158,576 B
  hipFuncSetAttribute((const void*)k_eigen, hipFuncAttributeMaxDynamicSharedMemorySize, EIG_SMEM);
  k_eigen<<<dim3(256), dim3(1024), EIG_SMEM, stream>>>(G, scal);
  k_tr<<<dim3(96,24), dim3(256), 0, stream>>>(W1, W1t, 768, 3072);
  k_tr<<<dim3(24,96), dim3(256), 0, stream>>>(W2, W2t, 3072, 768);
  k_tr<<<dim3(16,24), dim3(256), 0, stream>>>(Wp, Wpt, 768, 512);
  k_gemm<1><<<dim3(48,28), dim3(256), 0, stream>>>(aggbf, W1t, b1, (void*)h1, 1792, 3072, 768);
  k_gemm<2><<<dim3(12,28), dim3(256), 0, stream>>>(h1, W2t, b2, (void*)hbuf, 1792, 768, 3072);
  k_ln<<<dim3(448), dim3(256), 0, stream>>>(hbuf, gam, bet, hn);
  k_gemm<3><<<dim3(8,28), dim3(256), 0, stream>>>(hn, Wpt, nullptr, (void*)tok, 1792, 512, 768);
  k_head<<<dim3(256), dim3(256), 0, stream>>>(tok, ce, clsW, clsb, lgs, out);
  k_fin<<<dim3(1), dim3(64), 0, stream>>>(scal, out);
}